// Round 1
// baseline (788.028 us; speedup 1.0000x reference)
//
#include <hip/hip_runtime.h>

#define SEQ    512
#define DM     512
#define DI     1024
#define NH     16
#define HD     64
#define DS     64
#define CONVD  1152
#define DPROJ  2192

typedef __attribute__((ext_vector_type(8))) short bf16x8;
typedef __attribute__((ext_vector_type(4))) float floatx4;

__device__ __forceinline__ unsigned int f2bf(float f) {
  unsigned int u = __float_as_uint(f);
  u += 0x7FFFu + ((u >> 16) & 1u);   // round-to-nearest-even
  return u >> 16;
}
__device__ __forceinline__ int pack2(float a, float b) {
  return (int)(f2bf(a) | (f2bf(b) << 16));
}
__device__ __forceinline__ float sigmoidf_(float x) { return 1.f / (1.f + __expf(-x)); }
__device__ __forceinline__ float siluf_(float x) { return x * sigmoidf_(x); }

// ---------------------------------------------------------------------------
// Generic C = A * B^T GEMM, fp32 in (converted to bf16 in staging), fp32 out.
// A: M x K row-major (lda=K). B: N x K row-major (ldb=K). Tile 128x128, BK=32.
// EPI 0: plain store (guard gn < Nvalid)
// EPI 1: v += e0[m%1024][gn] (residual X); store Xcat[m%1024][(m/1024)*512+gn]
// EPI 2: zg = sigmoid(v + e0[gn]); C = zg*e1[gm][gn] + (1-zg)*e1[gm][512+gn]
// EPI 3: C = v + e0[gn]   (bias)
// ---------------------------------------------------------------------------
template<int EPI>
__global__ __launch_bounds__(256) void gemm_bt(
    const float* __restrict__ A, const float* __restrict__ B,
    float* __restrict__ C, const int K, const int Nvalid, const int ldc,
    const float* __restrict__ e0, const float* __restrict__ e1)
{
  __shared__ short As[128 * 40];   // rows padded 32->40 shorts (80B) for banks
  __shared__ short Bs[128 * 40];
  const int tid = threadIdx.x;
  const int m0 = blockIdx.y << 7, n0 = blockIdx.x << 7;
  const int lane = tid & 63;
  const int wm = ((tid >> 7) & 1) << 6;
  const int wn = ((tid >> 6) & 1) << 6;
  const int srow = tid >> 1, scol = (tid & 1) << 4;
  floatx4 acc[4][4];
#pragma unroll
  for (int i = 0; i < 4; i++)
#pragma unroll
    for (int j = 0; j < 4; j++) acc[i][j] = (floatx4)0.f;

  const float* ap = A + (size_t)(m0 + srow) * K + scol;
  const float* bp = B + (size_t)(n0 + srow) * K + scol;
  const bool bok = (n0 + srow) < Nvalid;
  short* arow = &As[srow * 40 + scol];
  short* brow = &Bs[srow * 40 + scol];
  const int r16 = lane & 15, q8 = (lane >> 4) << 3;

  for (int k0 = 0; k0 < K; k0 += 32) {
    float4 a0 = *(const float4*)(ap + k0);
    float4 a1 = *(const float4*)(ap + k0 + 4);
    float4 a2 = *(const float4*)(ap + k0 + 8);
    float4 a3 = *(const float4*)(ap + k0 + 12);
    float4 z4; z4.x = z4.y = z4.z = z4.w = 0.f;
    float4 b0 = z4, b1 = z4, b2 = z4, b3 = z4;
    if (bok) {
      b0 = *(const float4*)(bp + k0);
      b1 = *(const float4*)(bp + k0 + 4);
      b2 = *(const float4*)(bp + k0 + 8);
      b3 = *(const float4*)(bp + k0 + 12);
    }
    __syncthreads();
    ((int4*)arow)[0] = make_int4(pack2(a0.x,a0.y), pack2(a0.z,a0.w), pack2(a1.x,a1.y), pack2(a1.z,a1.w));
    ((int4*)arow)[1] = make_int4(pack2(a2.x,a2.y), pack2(a2.z,a2.w), pack2(a3.x,a3.y), pack2(a3.z,a3.w));
    ((int4*)brow)[0] = make_int4(pack2(b0.x,b0.y), pack2(b0.z,b0.w), pack2(b1.x,b1.y), pack2(b1.z,b1.w));
    ((int4*)brow)[1] = make_int4(pack2(b2.x,b2.y), pack2(b2.z,b2.w), pack2(b3.x,b3.y), pack2(b3.z,b3.w));
    __syncthreads();
    bf16x8 af[4], bfv[4];
#pragma unroll
    for (int i = 0; i < 4; i++) af[i]  = *(const bf16x8*)&As[(wm + i*16 + r16)*40 + q8];
#pragma unroll
    for (int i = 0; i < 4; i++) bfv[i] = *(const bf16x8*)&Bs[(wn + i*16 + r16)*40 + q8];
#pragma unroll
    for (int i = 0; i < 4; i++)
#pragma unroll
      for (int j = 0; j < 4; j++)
        acc[i][j] = __builtin_amdgcn_mfma_f32_16x16x32_bf16(af[i], bfv[j], acc[i][j], 0, 0, 0);
  }

  const int er = (lane >> 4) << 2;
#pragma unroll
  for (int i = 0; i < 4; i++) {
#pragma unroll
    for (int j = 0; j < 4; j++) {
#pragma unroll
      for (int r = 0; r < 4; r++) {
        const int gm = m0 + wm + i*16 + er + r;
        const int gn = n0 + wn + j*16 + r16;
        float v = acc[i][j][r];
        if (EPI == 0) {
          if (gn < Nvalid) C[(size_t)gm * ldc + gn] = v;
        } else if (EPI == 1) {
          const int mm = gm & 1023;
          v += e0[(size_t)mm * DM + gn];
          C[(size_t)mm * DI + ((gm >> 10) << 9) + gn] = v;
        } else if (EPI == 2) {
          const float zg = sigmoidf_(v + e0[gn]);
          C[(size_t)gm * ldc + gn] =
              zg * e1[(size_t)gm * DI + gn] + (1.f - zg) * e1[(size_t)gm * DI + DM + gn];
        } else {
          C[(size_t)gm * ldc + gn] = v + e0[gn];
        }
      }
    }
  }
}

// ---------------------------------------------------------------------------
__global__ void embed_k(const int* __restrict__ ids, const float* __restrict__ emb,
                        float* __restrict__ X) {
  const int m = blockIdx.x;
  const int row = ids[m];
  const float4* s = (const float4*)(emb + (size_t)row * DM);
  float4* d = (float4*)(X + (size_t)m * DM);
  d[threadIdx.x] = s[threadIdx.x];
}

// dt = softplus(zx[..,2176+h] + dt_bias[h]); dA = exp(dt * (-exp(A_log[h])))
__global__ void dtda_k(const float* __restrict__ zx, const float* __restrict__ dtb,
                       const float* __restrict__ alog, float* __restrict__ dtt,
                       float* __restrict__ dAt) {
  const int b = blockIdx.x;
  for (int i = threadIdx.x; i < NH * SEQ; i += blockDim.x) {
    const int h = i >> 9, t = i & 511;
    const float v = zx[(size_t)(b * SEQ + t) * DPROJ + 2176 + h] + dtb[h];
    const float dt = (v > 15.f) ? v : log1pf(__expf(v));
    const float A = -__expf(alog[h]);
    dtt[(b * NH + h) * SEQ + t] = dt;
    dAt[(b * NH + h) * SEQ + t] = __expf(dt * A);
  }
}

// Depthwise causal conv (fwd) / anticausal with flipped taps (bwd) + bias + silu.
// Output natural-time layout xact[dir][b][t][1152].
__global__ __launch_bounds__(256) void conv_k(const float* __restrict__ zx,
    const float* __restrict__ cw, const float* __restrict__ cb, float* __restrict__ xact) {
  const int t0 = blockIdx.x << 4;
  const int b = blockIdx.y;
  const int dir = blockIdx.z;
  const float* src = zx + (size_t)b * SEQ * DPROJ + DI;   // xBC slice
  float* dst = xact + (size_t)(dir * 2 + b) * SEQ * CONVD;
  for (int cc = 0; cc < 5; ++cc) {
    const int c = cc * 256 + threadIdx.x;
    if (c >= CONVD) break;
    const float w0 = cw[c*4+0], w1 = cw[c*4+1], w2 = cw[c*4+2], w3 = cw[c*4+3];
    const float bias = cb[c];
    if (dir == 0) {
      float xm3 = (t0 - 3 >= 0) ? src[(size_t)(t0-3) * DPROJ + c] : 0.f;
      float xm2 = (t0 - 2 >= 0) ? src[(size_t)(t0-2) * DPROJ + c] : 0.f;
      float xm1 = (t0 - 1 >= 0) ? src[(size_t)(t0-1) * DPROJ + c] : 0.f;
      for (int tt = 0; tt < 16; ++tt) {
        const int t = t0 + tt;
        const float x0 = src[(size_t)t * DPROJ + c];
        const float a = bias + w0*xm3 + w1*xm2 + w2*xm1 + w3*x0;
        dst[(size_t)t * CONVD + c] = siluf_(a);
        xm3 = xm2; xm2 = xm1; xm1 = x0;
      }
    } else {
      // y[t] = bias + w3*x[t] + w2*x[t+1] + w1*x[t+2] + w0*x[t+3]
      float x0  = src[(size_t)t0 * DPROJ + c];
      float xp1 = (t0 + 1 < SEQ) ? src[(size_t)(t0+1) * DPROJ + c] : 0.f;
      float xp2 = (t0 + 2 < SEQ) ? src[(size_t)(t0+2) * DPROJ + c] : 0.f;
      float xp3 = (t0 + 3 < SEQ) ? src[(size_t)(t0+3) * DPROJ + c] : 0.f;
      for (int tt = 0; tt < 16; ++tt) {
        const int t = t0 + tt;
        const float a = bias + w3*x0 + w2*xp1 + w1*xp2 + w0*xp3;
        dst[(size_t)t * CONVD + c] = siluf_(a);
        x0 = xp1; xp1 = xp2; xp2 = xp3;
        const int tn = t + 4;
        xp3 = (tn < SEQ) ? src[(size_t)tn * DPROJ + c] : 0.f;
      }
    }
  }
}

// SSD scan. Block = (dir,b,h,p-half). Thread = (p in 32, n-octet in 8);
// 8 states per thread in registers. dir=1 processes natural time descending.
__global__ __launch_bounds__(256) void scan_k(const float* __restrict__ xact,
    const float* __restrict__ dtt, const float* __restrict__ dAt,
    float* __restrict__ ynat) {
  const int bid = blockIdx.x;
  const int dir = bid >> 6, b = (bid >> 5) & 1, h = (bid >> 1) & 15, ph = bid & 1;
  const int tid = threadIdx.x;
  const int pl = tid & 31;
  const int p = ph * 32 + pl;
  const int nq = tid >> 5;
  const int n0 = nq << 3;
  const float* src = xact + (size_t)(dir * 2 + b) * SEQ * CONVD;
  const float* dtp = dtt + (b * NH + h) * SEQ;
  const float* dap = dAt + (b * NH + h) * SEQ;
  float* yrow = ynat + (size_t)(dir * 2 + b) * SEQ * DI + h * HD;
  __shared__ float Bsh[16][64];
  __shared__ float Csh[16][64];
  __shared__ float yp[8][16][33];
  float hst[8];
#pragma unroll
  for (int j = 0; j < 8; j++) hst[j] = 0.f;
  const int sr = tid >> 6, scc = tid & 63;

  for (int c0 = 0; c0 < SEQ; c0 += 16) {
#pragma unroll
    for (int rr = 0; rr < 4; ++rr) {
      const int row = sr * 4 + rr;
      const int tn = dir ? (SEQ - 1 - (c0 + row)) : (c0 + row);
      Bsh[row][scc] = src[(size_t)tn * CONVD + DI + scc];
      Csh[row][scc] = src[(size_t)tn * CONVD + DI + DS + scc];
    }
    const int q = tid & 15;
    const int tq = dir ? (SEQ - 1 - (c0 + q)) : (c0 + q);
    const float dt_pre = dtp[tq];
    const float dA_pre = dap[tq];
    float xch[16];
#pragma unroll
    for (int s = 0; s < 16; ++s) {
      const int tn = dir ? (SEQ - 1 - (c0 + s)) : (c0 + s);
      xch[s] = src[(size_t)tn * CONVD + h * HD + p];
    }
    __syncthreads();
#pragma unroll
    for (int s = 0; s < 16; ++s) {
      const float dts = __shfl(dt_pre, s);
      const float das = __shfl(dA_pre, s);
      const float dtx = dts * xch[s];
      const float4 bv0 = *(const float4*)&Bsh[s][n0];
      const float4 bv1 = *(const float4*)&Bsh[s][n0 + 4];
      const float4 cv0 = *(const float4*)&Csh[s][n0];
      const float4 cv1 = *(const float4*)&Csh[s][n0 + 4];
      float ya;
      hst[0] = hst[0]*das + dtx*bv0.x; ya  = hst[0]*cv0.x;
      hst[1] = hst[1]*das + dtx*bv0.y; ya += hst[1]*cv0.y;
      hst[2] = hst[2]*das + dtx*bv0.z; ya += hst[2]*cv0.z;
      hst[3] = hst[3]*das + dtx*bv0.w; ya += hst[3]*cv0.w;
      hst[4] = hst[4]*das + dtx*bv1.x; ya += hst[4]*cv1.x;
      hst[5] = hst[5]*das + dtx*bv1.y; ya += hst[5]*cv1.y;
      hst[6] = hst[6]*das + dtx*bv1.z; ya += hst[6]*cv1.z;
      hst[7] = hst[7]*das + dtx*bv1.w; ya += hst[7]*cv1.w;
      yp[nq][s][pl] = ya;
    }
    __syncthreads();
    {
      const int t = tid >> 4;
      const int pp = (tid & 15) << 1;
      const int tn = dir ? (SEQ - 1 - (c0 + t)) : (c0 + t);
#pragma unroll
      for (int qq = 0; qq < 2; ++qq) {
        const int pc = pp + qq;
        float s0 = 0.f;
#pragma unroll
        for (int j = 0; j < 8; ++j) s0 += yp[j][t][pc];
        yrow[(size_t)tn * DI + ph * 32 + pc] = s0;
      }
    }
    __syncthreads();
  }
}

// gated = (y + xs*D[h]) * silu(z); A2 = rmsnorm(gated) * norm_w
__global__ __launch_bounds__(256) void p2_k(const float* __restrict__ ynat,
    const float* __restrict__ xact, const float* __restrict__ zx,
    const float* __restrict__ dss, const float* __restrict__ nw,
    float* __restrict__ A2) {
  const int m2 = blockIdx.x;
  const int e4 = threadIdx.x << 2;
  const float4 y4 = *(const float4*)(ynat + (size_t)m2 * DI + e4);
  const float4 x4 = *(const float4*)(xact + (size_t)m2 * CONVD + e4);
  const float4 z4 = *(const float4*)(zx + (size_t)(m2 & 1023) * DPROJ + e4);
  const float d = dss[e4 >> 6];
  float4 g;
  g.x = (y4.x + x4.x * d) * siluf_(z4.x);
  g.y = (y4.y + x4.y * d) * siluf_(z4.y);
  g.z = (y4.z + x4.z * d) * siluf_(z4.z);
  g.w = (y4.w + x4.w * d) * siluf_(z4.w);
  float ss = g.x*g.x + g.y*g.y + g.z*g.z + g.w*g.w;
#pragma unroll
  for (int m = 32; m >= 1; m >>= 1) ss += __shfl_xor(ss, m);
  __shared__ float red[4];
  if ((threadIdx.x & 63) == 0) red[threadIdx.x >> 6] = ss;
  __syncthreads();
  const float tot = red[0] + red[1] + red[2] + red[3];
  const float sc = rsqrtf(tot * (1.f / 1024.f) + 1e-5f);
  const float4 w4 = *(const float4*)(nw + e4);
  float4 o;
  o.x = g.x * sc * w4.x; o.y = g.y * sc * w4.y;
  o.z = g.z * sc * w4.z; o.w = g.w * sc * w4.w;
  *(float4*)(A2 + (size_t)m2 * DI + e4) = o;
}

__global__ __launch_bounds__(128) void fnorm_k(const float* __restrict__ X,
    const float* __restrict__ w, float* __restrict__ out) {
  const int m = blockIdx.x;
  const int e4 = threadIdx.x << 2;
  const float4 x4 = *(const float4*)(X + (size_t)m * DM + e4);
  float ss = x4.x*x4.x + x4.y*x4.y + x4.z*x4.z + x4.w*x4.w;
#pragma unroll
  for (int mm = 32; mm >= 1; mm >>= 1) ss += __shfl_xor(ss, mm);
  __shared__ float red[2];
  if ((threadIdx.x & 63) == 0) red[threadIdx.x >> 6] = ss;
  __syncthreads();
  const float tot = red[0] + red[1];
  const float sc = rsqrtf(tot * (1.f / 512.f) + 1e-5f);
  const float4 w4 = *(const float4*)(w + e4);
  float4 o;
  o.x = x4.x * sc * w4.x; o.y = x4.y * sc * w4.y;
  o.z = x4.z * sc * w4.z; o.w = x4.w * sc * w4.w;
  *(float4*)(out + (size_t)m * DM + e4) = o;
}

// ---------------------------------------------------------------------------
extern "C" void kernel_launch(void* const* d_in, const int* in_sizes, int n_in,
                              void* d_out, int out_size, void* d_ws, size_t ws_size,
                              hipStream_t stream) {
  (void)in_sizes; (void)n_in; (void)out_size; (void)ws_size;
  const int*   ids  = (const int*)d_in[0];
  // d_in[1] = padding_mask: all false -> flip is full reversal (handled analytically)
  const float* emb  = (const float*)d_in[2];
  const float* wi   = (const float*)d_in[3];
  const float* cw   = (const float*)d_in[4];
  const float* cb   = (const float*)d_in[5];
  const float* dtb  = (const float*)d_in[6];
  const float* alog = (const float*)d_in[7];
  const float* dss  = (const float*)d_in[8];
  const float* nw   = (const float*)d_in[9];
  const float* wo   = (const float*)d_in[10];
  const float* aw   = (const float*)d_in[11];
  const float* ab   = (const float*)d_in[12];
  const float* nfw  = (const float*)d_in[13];
  const float* lmw  = (const float*)d_in[14];
  const float* lmb  = (const float*)d_in[15];
  float* out = (float*)d_out;

  float* ws   = (float*)d_ws;                       // ~44 MB total
  float* X    = ws;                                 // 1024*512
  float* zx   = X    + (size_t)1024 * 512;          // 1024*2192
  float* xact = zx   + (size_t)1024 * 2192;         // 4*512*1152
  float* dtt  = xact + (size_t)4 * 512 * 1152;      // 2*16*512
  float* dAt  = dtt  + (size_t)2 * 16 * 512;        // 2*16*512
  float* ynat = dAt  + (size_t)2 * 16 * 512;        // 4*512*1024
  float* A2   = ynat + (size_t)4 * 512 * 1024;      // 2048*1024
  float* Xcat = A2   + (size_t)2048 * 1024;         // 1024*1024
  float* hn   = Xcat + (size_t)1024 * 1024;         // 1024*512

  embed_k<<<dim3(1024), dim3(128), 0, stream>>>(ids, emb, X);
  for (int layer = 0; layer < 2; ++layer) {
    gemm_bt<0><<<dim3(18, 8), dim3(256), 0, stream>>>(
        X, wi + (size_t)layer * 2192 * 512, zx, 512, 2192, 2192, nullptr, nullptr);
    dtda_k<<<dim3(2), dim3(256), 0, stream>>>(zx, dtb + layer * 16, alog + layer * 16, dtt, dAt);
    conv_k<<<dim3(32, 2, 2), dim3(256), 0, stream>>>(zx, cw + (size_t)layer * 1152 * 4,
                                                     cb + (size_t)layer * 1152, xact);
    scan_k<<<dim3(128), dim3(256), 0, stream>>>(xact, dtt, dAt, ynat);
    p2_k<<<dim3(2048), dim3(256), 0, stream>>>(ynat, xact, zx, dss + layer * 16,
                                               nw + (size_t)layer * 1024, A2);
    gemm_bt<1><<<dim3(4, 16), dim3(256), 0, stream>>>(
        A2, wo + (size_t)layer * 512 * 1024, Xcat, 1024, 512, 512, X, nullptr);
    gemm_bt<2><<<dim3(4, 8), dim3(256), 0, stream>>>(
        Xcat, aw, X, 1024, 512, 512, ab, Xcat);
  }
  fnorm_k<<<dim3(1024), dim3(128), 0, stream>>>(X, nfw, hn);
  gemm_bt<3><<<dim3(256, 8), dim3(256), 0, stream>>>(
      hn, lmw, out, 512, 32768, 32768, lmb, nullptr);
}

// Round 2
// 571.749 us; speedup vs baseline: 1.3783x; 1.3783x over previous
//
#include <hip/hip_runtime.h>

#define SEQ    512
#define DM     512
#define DI     1024
#define NH     16
#define DS     64
#define CONVD  1152
#define DPROJ  2192
#define NPADIN 2304

typedef __attribute__((ext_vector_type(8))) short bf16x8;
typedef __attribute__((ext_vector_type(4))) float floatx4;

__device__ __forceinline__ unsigned int f2bf(float f) {
  unsigned int u = __float_as_uint(f);
  u += 0x7FFFu + ((u >> 16) & 1u);   // RNE
  return u >> 16;
}
__device__ __forceinline__ ushort4 cvt4(float4 v) {
  ushort4 o;
  o.x = (unsigned short)f2bf(v.x); o.y = (unsigned short)f2bf(v.y);
  o.z = (unsigned short)f2bf(v.z); o.w = (unsigned short)f2bf(v.w);
  return o;
}
__device__ __forceinline__ float sigmoidf_(float x) { return 1.f / (1.f + __expf(-x)); }
__device__ __forceinline__ float siluf_(float x) { return x * sigmoidf_(x); }

__device__ __forceinline__ void gl16(const void* g, void* l) {
  __builtin_amdgcn_global_load_lds(
      (const __attribute__((address_space(1))) unsigned int*)g,
      (__attribute__((address_space(3))) unsigned int*)l, 16, 0, 0);
}

// ---------------------------------------------------------------------------
// bf16 C = A * B^T GEMM, m97 pattern: global_load_lds width 16, unpadded
// 64B LDS rows, 2x2 waves, frag grid (BM/32)x(BN/32) per wave.
// EPI 0: fp32 store, guard gn < Nvalid (in_proj -> zx)
// EPI 1: v += Xf[mm][gn]; Xcat[f+b16][mm][(gm>>10)*512+gn] (out_proj)
// EPI 2: zg=sigmoid(v+bias); xn = zg*Xcatf[..gn] + (1-zg)*Xcatf[..512+gn];
//        store Xf fp32 + Xb bf16 (aggr)
// EPI 3: fp32 store v + bias (lm_head)
// ---------------------------------------------------------------------------
template<int BM, int BN, int EPI>
__global__ __launch_bounds__(256) void gemm_bf(
    const short* __restrict__ A, const short* __restrict__ B,
    float* __restrict__ C, const int K, const int Nvalid, const int ldc,
    const float* __restrict__ e0, const float* __restrict__ e1,
    unsigned short* __restrict__ o2)
{
  constexpr int FM = BM / 32, FN = BN / 32;
  constexpr int CA = BM / 64, CB = BN / 64;
  __shared__ short As[BM * 32];
  __shared__ short Bs[BN * 32];
  const int tid = threadIdx.x, lane = tid & 63, wave = tid >> 6;
  const int m0 = blockIdx.y * BM, n0 = blockIdx.x * BN;
  const int wm = (wave >> 1) * (BM / 2), wn = (wave & 1) * (BN / 2);
  const int lrow = lane >> 2, lchk = (lane & 3) << 3;
  const short* agp = A + (size_t)(m0 + wave * (CA * 16) + lrow) * K + lchk;
  const short* bgp = B + (size_t)(n0 + wave * (CB * 16) + lrow) * K + lchk;
  short* albase = &As[wave * (CA * 16) * 32];
  short* blbase = &Bs[wave * (CB * 16) * 32];
  const int r16 = lane & 15, q8 = (lane >> 4) << 3;

  floatx4 acc[FM][FN];
#pragma unroll
  for (int i = 0; i < FM; i++)
#pragma unroll
    for (int j = 0; j < FN; j++) acc[i][j] = (floatx4)0.f;

  for (int k0 = 0; k0 < K; k0 += 32) {
#pragma unroll
    for (int i = 0; i < CA; ++i)
      gl16(agp + (size_t)i * 16 * K + k0, albase + i * 16 * 32);
#pragma unroll
    for (int i = 0; i < CB; ++i)
      gl16(bgp + (size_t)i * 16 * K + k0, blbase + i * 16 * 32);
    __syncthreads();   // drains vmcnt -> LDS tiles valid
    bf16x8 afr[FM], bfr[FN];
#pragma unroll
    for (int i = 0; i < FM; i++) afr[i] = *(const bf16x8*)&As[(wm + i * 16 + r16) * 32 + q8];
#pragma unroll
    for (int j = 0; j < FN; j++) bfr[j] = *(const bf16x8*)&Bs[(wn + j * 16 + r16) * 32 + q8];
#pragma unroll
    for (int i = 0; i < FM; i++)
#pragma unroll
      for (int j = 0; j < FN; j++)
        acc[i][j] = __builtin_amdgcn_mfma_f32_16x16x32_bf16(afr[i], bfr[j], acc[i][j], 0, 0, 0);
    __syncthreads();   // all frag reads done before next staging
  }

  const int er = (lane >> 4) << 2;
#pragma unroll
  for (int i = 0; i < FM; ++i)
#pragma unroll
    for (int j = 0; j < FN; ++j)
#pragma unroll
      for (int r = 0; r < 4; ++r) {
        const int gm = m0 + wm + i * 16 + er + r;
        const int gn = n0 + wn + j * 16 + r16;
        float v = acc[i][j][r];
        if (EPI == 0) {
          if (gn < Nvalid) C[(size_t)gm * ldc + gn] = v;
        } else if (EPI == 1) {
          const int mm = gm & 1023;
          v += e0[(size_t)mm * DM + gn];
          const size_t idx = (size_t)mm * DI + ((gm >> 10) << 9) + gn;
          C[idx] = v;
          o2[idx] = (unsigned short)f2bf(v);
        } else if (EPI == 2) {
          const float zg = sigmoidf_(v + e0[gn]);
          const float xn = zg * e1[(size_t)gm * DI + gn] +
                           (1.f - zg) * e1[(size_t)gm * DI + DM + gn];
          const size_t idx = (size_t)gm * DM + gn;
          C[idx] = xn;
          o2[idx] = (unsigned short)f2bf(xn);
        } else {
          C[(size_t)gm * ldc + gn] = v + e0[gn];
        }
      }
}

// ---------------------------------------------------------------------------
__global__ void cvt_k(const float* __restrict__ s, unsigned short* __restrict__ d,
                      const int n4) {
  const int stride = gridDim.x * blockDim.x;
  for (int i = blockIdx.x * blockDim.x + threadIdx.x; i < n4; i += stride)
    ((ushort4*)d)[i] = cvt4(((const float4*)s)[i]);
}

// wi (2192 x 512) -> padded bf16 (2304 x 512), pad rows zeroed every call
__global__ void cvt_wi_k(const float* __restrict__ wi, unsigned short* __restrict__ d) {
  const int row = blockIdx.x, l = blockIdx.y;
  ushort4 o; o.x = o.y = o.z = o.w = 0;
  if (row < DPROJ)
    o = cvt4(((const float4*)(wi + ((size_t)l * DPROJ + row) * DM))[threadIdx.x]);
  ((ushort4*)(d + ((size_t)l * NPADIN + row) * DM))[threadIdx.x] = o;
}

__global__ void embed_k(const int* __restrict__ ids, const float* __restrict__ emb,
                        float* __restrict__ Xf, unsigned short* __restrict__ Xb) {
  const int m = blockIdx.x;
  const int row = ids[m];
  float4 v = ((const float4*)(emb + (size_t)row * DM))[threadIdx.x];
  ((float4*)(Xf + (size_t)m * DM))[threadIdx.x] = v;
  ((ushort4*)(Xb + (size_t)m * DM))[threadIdx.x] = cvt4(v);
}

__global__ void dtda_k(const float* __restrict__ zx, const float* __restrict__ dtb,
                       const float* __restrict__ alog, float* __restrict__ dtt,
                       float* __restrict__ dAt) {
  const int b = blockIdx.x >> 4, h = blockIdx.x & 15;
  const float bias = dtb[h];
  const float A = -__expf(alog[h]);
  for (int t = threadIdx.x; t < SEQ; t += 256) {
    const float v = zx[(size_t)(b * SEQ + t) * DPROJ + 2176 + h] + bias;
    const float dt = (v > 15.f) ? v : log1pf(__expf(v));
    dtt[(b * NH + h) * SEQ + t] = dt;
    dAt[(b * NH + h) * SEQ + t] = __expf(dt * A);
  }
}

// Depthwise causal conv (fwd) / anticausal flipped taps (bwd) + bias + silu.
__global__ __launch_bounds__(256) void conv_k(const float* __restrict__ zx,
    const float* __restrict__ cw, const float* __restrict__ cb, float* __restrict__ xact) {
  const int t0 = blockIdx.x << 4;
  const int b = blockIdx.y;
  const int dir = blockIdx.z;
  const float* src = zx + (size_t)b * SEQ * DPROJ + DI;
  float* dst = xact + (size_t)(dir * 2 + b) * SEQ * CONVD;
  for (int cc = 0; cc < 5; ++cc) {
    const int c = cc * 256 + threadIdx.x;
    if (c >= CONVD) break;
    const float w0 = cw[c*4+0], w1 = cw[c*4+1], w2 = cw[c*4+2], w3 = cw[c*4+3];
    const float bias = cb[c];
    if (dir == 0) {
      float xm3 = (t0 - 3 >= 0) ? src[(size_t)(t0-3) * DPROJ + c] : 0.f;
      float xm2 = (t0 - 2 >= 0) ? src[(size_t)(t0-2) * DPROJ + c] : 0.f;
      float xm1 = (t0 - 1 >= 0) ? src[(size_t)(t0-1) * DPROJ + c] : 0.f;
      for (int tt = 0; tt < 16; ++tt) {
        const int t = t0 + tt;
        const float x0 = src[(size_t)t * DPROJ + c];
        dst[(size_t)t * CONVD + c] = siluf_(bias + w0*xm3 + w1*xm2 + w2*xm1 + w3*x0);
        xm3 = xm2; xm2 = xm1; xm1 = x0;
      }
    } else {
      float x0  = src[(size_t)t0 * DPROJ + c];
      float xp1 = (t0 + 1 < SEQ) ? src[(size_t)(t0+1) * DPROJ + c] : 0.f;
      float xp2 = (t0 + 2 < SEQ) ? src[(size_t)(t0+2) * DPROJ + c] : 0.f;
      float xp3 = (t0 + 3 < SEQ) ? src[(size_t)(t0+3) * DPROJ + c] : 0.f;
      for (int tt = 0; tt < 16; ++tt) {
        const int t = t0 + tt;
        dst[(size_t)t * CONVD + c] = siluf_(bias + w3*x0 + w2*xp1 + w1*xp2 + w0*xp3);
        x0 = xp1; xp1 = xp2; xp2 = xp3;
        const int tn = t + 4;
        xp3 = (tn < SEQ) ? src[(size_t)tn * DPROJ + c] : 0.f;
      }
    }
  }
}

// SSD scan. Block = (dir,b,h,p-half,n-half): 256 blocks. Thread = (p in 32,
// n-quad in 8): 4 states/thread. dt/dA via block-uniform scalar loads.
// Output: yn[nh][dir*2+b][t][DI] (two halves summed by p2_k).
__global__ __launch_bounds__(256) void scan_k(const float* __restrict__ xact,
    const float* __restrict__ dtt, const float* __restrict__ dAt,
    float* __restrict__ yn) {
  const int bid = blockIdx.x;
  const int dir = bid >> 7, b = (bid >> 6) & 1, h = (bid >> 2) & 15;
  const int ph = (bid >> 1) & 1, nh = bid & 1;
  const int tid = threadIdx.x, pl = tid & 31, nq = tid >> 5;
  const int p = ph * 32 + pl, nb = nq << 2;
  const float* src = xact + (size_t)(dir * 2 + b) * SEQ * CONVD;
  const float* dtp = dtt + (b * NH + h) * SEQ;
  const float* dap = dAt + (b * NH + h) * SEQ;
  float* yrow = yn + (size_t)nh * (4 * SEQ * DI) + (size_t)(dir * 2 + b) * SEQ * DI
              + h * 64 + ph * 32;
  __shared__ float Bsh[16][32];
  __shared__ float Csh[16][32];
  __shared__ float yp[8][16][33];
  float hs[4] = {0.f, 0.f, 0.f, 0.f};
  const int srow = tid >> 4, scol = (tid & 15) << 1;

  for (int c0 = 0; c0 < SEQ; c0 += 16) {
    {
      const int tn = dir ? (SEQ - 1 - (c0 + srow)) : (c0 + srow);
      const float* bp = src + (size_t)tn * CONVD + DI + nh * 32 + scol;
      *(float2*)&Bsh[srow][scol] = *(const float2*)bp;
      *(float2*)&Csh[srow][scol] = *(const float2*)(bp + DS);
    }
    float xch[16];
#pragma unroll
    for (int s = 0; s < 16; ++s) {
      const int tn = dir ? (SEQ - 1 - (c0 + s)) : (c0 + s);
      xch[s] = src[(size_t)tn * CONVD + h * 64 + p];
    }
    __syncthreads();
#pragma unroll
    for (int s = 0; s < 16; ++s) {
      const int tu = dir ? (SEQ - 1 - (c0 + s)) : (c0 + s);
      const float dts = dtp[tu];     // block-uniform -> s_load
      const float das = dap[tu];
      const float dtx = dts * xch[s];
      const float4 b4 = *(const float4*)&Bsh[s][nb];
      const float4 c4 = *(const float4*)&Csh[s][nb];
      float ya;
      hs[0] = hs[0] * das + dtx * b4.x; ya  = hs[0] * c4.x;
      hs[1] = hs[1] * das + dtx * b4.y; ya += hs[1] * c4.y;
      hs[2] = hs[2] * das + dtx * b4.z; ya += hs[2] * c4.z;
      hs[3] = hs[3] * das + dtx * b4.w; ya += hs[3] * c4.w;
      yp[nq][s][pl] = ya;
    }
    __syncthreads();
    {
      const int rt = tid >> 4, rp = (tid & 15) << 1;
      const int tn = dir ? (SEQ - 1 - (c0 + rt)) : (c0 + rt);
      float s0 = 0.f, s1 = 0.f;
#pragma unroll
      for (int j = 0; j < 8; ++j) { s0 += yp[j][rt][rp]; s1 += yp[j][rt][rp + 1]; }
      float2 o; o.x = s0; o.y = s1;
      *(float2*)&yrow[(size_t)tn * DI + rp] = o;
    }
    __syncthreads();
  }
}

// gated = (y0+y1 + xs*D[h]) * silu(z); A2b = bf16(rmsnorm(gated) * norm_w)
__global__ __launch_bounds__(256) void p2_k(const float* __restrict__ yn,
    const float* __restrict__ xact, const float* __restrict__ zx,
    const float* __restrict__ dss, const float* __restrict__ nw,
    unsigned short* __restrict__ A2b) {
  const int m2 = blockIdx.x;
  const int e4 = threadIdx.x << 2;
  const float4 ya = *(const float4*)(yn + (size_t)m2 * DI + e4);
  const float4 yb = *(const float4*)(yn + (size_t)4 * SEQ * DI + (size_t)m2 * DI + e4);
  const float4 x4 = *(const float4*)(xact + (size_t)m2 * CONVD + e4);
  const float4 z4 = *(const float4*)(zx + (size_t)(m2 & 1023) * DPROJ + e4);
  const float d = dss[e4 >> 6];
  float4 g;
  g.x = (ya.x + yb.x + x4.x * d) * siluf_(z4.x);
  g.y = (ya.y + yb.y + x4.y * d) * siluf_(z4.y);
  g.z = (ya.z + yb.z + x4.z * d) * siluf_(z4.z);
  g.w = (ya.w + yb.w + x4.w * d) * siluf_(z4.w);
  float ss = g.x*g.x + g.y*g.y + g.z*g.z + g.w*g.w;
#pragma unroll
  for (int m = 32; m >= 1; m >>= 1) ss += __shfl_xor(ss, m);
  __shared__ float red[4];
  if ((threadIdx.x & 63) == 0) red[threadIdx.x >> 6] = ss;
  __syncthreads();
  const float tot = red[0] + red[1] + red[2] + red[3];
  const float sc = rsqrtf(tot * (1.f / 1024.f) + 1e-5f);
  const float4 w4 = *(const float4*)(nw + e4);
  float4 o;
  o.x = g.x * sc * w4.x; o.y = g.y * sc * w4.y;
  o.z = g.z * sc * w4.z; o.w = g.w * sc * w4.w;
  ((ushort4*)(A2b + (size_t)m2 * DI))[threadIdx.x] = cvt4(o);
}

__global__ __launch_bounds__(128) void fnorm_k(const float* __restrict__ X,
    const float* __restrict__ w, unsigned short* __restrict__ outb) {
  const int m = blockIdx.x;
  const int e4 = threadIdx.x << 2;
  const float4 x4 = *(const float4*)(X + (size_t)m * DM + e4);
  float ss = x4.x*x4.x + x4.y*x4.y + x4.z*x4.z + x4.w*x4.w;
#pragma unroll
  for (int mm = 32; mm >= 1; mm >>= 1) ss += __shfl_xor(ss, mm);
  __shared__ float red[2];
  if ((threadIdx.x & 63) == 0) red[threadIdx.x >> 6] = ss;
  __syncthreads();
  const float tot = red[0] + red[1];
  const float sc = rsqrtf(tot * (1.f / 512.f) + 1e-5f);
  const float4 w4 = *(const float4*)(w + e4);
  float4 o;
  o.x = x4.x * sc * w4.x; o.y = x4.y * sc * w4.y;
  o.z = x4.z * sc * w4.z; o.w = x4.w * sc * w4.w;
  ((ushort4*)(outb + (size_t)m * DM))[threadIdx.x] = cvt4(o);
}

// ---------------------------------------------------------------------------
extern "C" void kernel_launch(void* const* d_in, const int* in_sizes, int n_in,
                              void* d_out, int out_size, void* d_ws, size_t ws_size,
                              hipStream_t stream) {
  (void)in_sizes; (void)n_in; (void)out_size; (void)ws_size;
  const int*   ids  = (const int*)d_in[0];
  const float* emb  = (const float*)d_in[2];
  const float* wi   = (const float*)d_in[3];
  const float* cw   = (const float*)d_in[4];
  const float* cb   = (const float*)d_in[5];
  const float* dtb  = (const float*)d_in[6];
  const float* alog = (const float*)d_in[7];
  const float* dss  = (const float*)d_in[8];
  const float* nw   = (const float*)d_in[9];
  const float* wo   = (const float*)d_in[10];
  const float* aw   = (const float*)d_in[11];
  const float* ab   = (const float*)d_in[12];
  const float* nfw  = (const float*)d_in[13];
  const float* lmw  = (const float*)d_in[14];
  const float* lmb  = (const float*)d_in[15];
  float* out = (float*)d_out;

  float* ws    = (float*)d_ws;
  float* Xf    = ws;                                 //  524288
  float* zx    = Xf    + (size_t)524288;             // 2244608
  float* xact  = zx    + (size_t)2244608;            // 2359296
  float* dtt   = xact  + (size_t)2359296;            //   16384
  float* dAt   = dtt   + (size_t)16384;              //   16384
  float* yn    = dAt   + (size_t)16384;              // 4194304 (2 halves)
  float* Xcatf = yn    + (size_t)4194304;            // 1048576
  unsigned short* Xb    = (unsigned short*)(Xcatf + (size_t)1048576);
  unsigned short* A2b   = Xb    + (size_t)524288;
  unsigned short* Xcatb = A2b   + (size_t)2097152;
  unsigned short* hnb   = Xcatb + (size_t)1048576;
  unsigned short* wiB   = hnb   + (size_t)524288;
  unsigned short* woB   = wiB   + (size_t)2359296;
  unsigned short* awB   = woB   + (size_t)1048576;
  unsigned short* lmwB  = awB   + (size_t)524288;

  cvt_wi_k<<<dim3(NPADIN, 2), dim3(128), 0, stream>>>(wi, wiB);
  cvt_k<<<dim3(1024), dim3(256), 0, stream>>>(wo, woB, 262144);
  cvt_k<<<dim3(512), dim3(256), 0, stream>>>(aw, awB, 131072);
  cvt_k<<<dim3(4096), dim3(256), 0, stream>>>(lmw, lmwB, 4194304);
  embed_k<<<dim3(1024), dim3(128), 0, stream>>>(ids, emb, Xf, Xb);

  for (int layer = 0; layer < 2; ++layer) {
    gemm_bf<128, 128, 0><<<dim3(18, 8), dim3(256), 0, stream>>>(
        (const short*)Xb, (const short*)(wiB + (size_t)layer * NPADIN * DM),
        zx, 512, 2192, 2192, nullptr, nullptr, nullptr);
    dtda_k<<<dim3(32), dim3(256), 0, stream>>>(zx, dtb + 16 * layer, alog + 16 * layer, dtt, dAt);
    conv_k<<<dim3(32, 2, 2), dim3(256), 0, stream>>>(zx, cw + (size_t)layer * 4608,
                                                     cb + (size_t)layer * 1152, xact);
    scan_k<<<dim3(256), dim3(256), 0, stream>>>(xact, dtt, dAt, yn);
    p2_k<<<dim3(2048), dim3(256), 0, stream>>>(yn, xact, zx, dss + 16 * layer,
                                               nw + (size_t)layer * 1024, A2b);
    gemm_bf<64, 128, 1><<<dim3(4, 32), dim3(256), 0, stream>>>(
        (const short*)A2b, (const short*)(woB + (size_t)layer * DM * DI),
        Xcatf, 1024, 512, 512, Xf, nullptr, Xcatb);
    gemm_bf<64, 64, 2><<<dim3(8, 16), dim3(256), 0, stream>>>(
        (const short*)Xcatb, (const short*)awB,
        Xf, 1024, 512, 512, ab, Xcatf, Xb);
  }
  fnorm_k<<<dim3(1024), dim3(128), 0, stream>>>(Xf, nfw, hnb);
  gemm_bf<128, 128, 3><<<dim3(256, 8), dim3(256), 0, stream>>>(
      (const short*)hnb, (const short*)lmwB, out, 512, 32768, 32768, lmb, nullptr, nullptr);
}

// Round 3
// 554.672 us; speedup vs baseline: 1.4207x; 1.0308x over previous
//
#include <hip/hip_runtime.h>

#define SEQ    512
#define DM     512
#define DI     1024
#define NH     16
#define DS     64
#define CONVD  1152
#define DPROJ  2192
#define NPADIN 2304

typedef __attribute__((ext_vector_type(8))) short bf16x8;
typedef __attribute__((ext_vector_type(4))) float floatx4;

__device__ __forceinline__ unsigned int f2bf(float f) {
  unsigned int u = __float_as_uint(f);
  u += 0x7FFFu + ((u >> 16) & 1u);   // RNE
  return u >> 16;
}
__device__ __forceinline__ ushort4 cvt4(float4 v) {
  ushort4 o;
  o.x = (unsigned short)f2bf(v.x); o.y = (unsigned short)f2bf(v.y);
  o.z = (unsigned short)f2bf(v.z); o.w = (unsigned short)f2bf(v.w);
  return o;
}
__device__ __forceinline__ float sigmoidf_(float x) { return 1.f / (1.f + __expf(-x)); }
__device__ __forceinline__ float siluf_(float x) { return x * sigmoidf_(x); }

__device__ __forceinline__ void gl16(const void* g, void* l) {
  __builtin_amdgcn_global_load_lds(
      (const __attribute__((address_space(1))) unsigned int*)g,
      (__attribute__((address_space(3))) unsigned int*)l, 16, 0, 0);
}

// ---------------------------------------------------------------------------
// bf16 C = A * B^T GEMM, m97 pattern (global_load_lds width16, 64B LDS rows).
// EPI 0: fp32 store, guard gn < Nvalid (in_proj -> zx)
// EPI 1: v += Xf[mm][gn]; Xcat[f+b16][mm][(gm>>10)*512+gn] (out_proj)
// EPI 2: zg=sigmoid(v+bias); xn = zg*Xcatf[..gn]+(1-zg)*Xcatf[..512+gn];
//        store Xf fp32 + Xb bf16 (aggr)
// EPI 3: fp32 store v + bias (lm_head)
// ---------------------------------------------------------------------------
template<int BM, int BN, int EPI>
__global__ __launch_bounds__(256) void gemm_bf(
    const short* __restrict__ A, const short* __restrict__ B,
    float* __restrict__ C, const int K, const int Nvalid, const int ldc,
    const float* __restrict__ e0, const float* __restrict__ e1,
    unsigned short* __restrict__ o2)
{
  constexpr int FM = BM / 32, FN = BN / 32;
  constexpr int CA = BM / 64, CB = BN / 64;
  __shared__ short As[BM * 32];
  __shared__ short Bs[BN * 32];
  const int tid = threadIdx.x, lane = tid & 63, wave = tid >> 6;
  const int m0 = blockIdx.y * BM, n0 = blockIdx.x * BN;
  const int wm = (wave >> 1) * (BM / 2), wn = (wave & 1) * (BN / 2);
  const int lrow = lane >> 2, lchk = (lane & 3) << 3;
  const short* agp = A + (size_t)(m0 + wave * (CA * 16) + lrow) * K + lchk;
  const short* bgp = B + (size_t)(n0 + wave * (CB * 16) + lrow) * K + lchk;
  short* albase = &As[wave * (CA * 16) * 32];
  short* blbase = &Bs[wave * (CB * 16) * 32];
  const int r16 = lane & 15, q8 = (lane >> 4) << 3;

  floatx4 acc[FM][FN];
#pragma unroll
  for (int i = 0; i < FM; i++)
#pragma unroll
    for (int j = 0; j < FN; j++) acc[i][j] = (floatx4)0.f;

  for (int k0 = 0; k0 < K; k0 += 32) {
#pragma unroll
    for (int i = 0; i < CA; ++i)
      gl16(agp + (size_t)i * 16 * K + k0, albase + i * 16 * 32);
#pragma unroll
    for (int i = 0; i < CB; ++i)
      gl16(bgp + (size_t)i * 16 * K + k0, blbase + i * 16 * 32);
    __syncthreads();
    bf16x8 afr[FM], bfr[FN];
#pragma unroll
    for (int i = 0; i < FM; i++) afr[i] = *(const bf16x8*)&As[(wm + i * 16 + r16) * 32 + q8];
#pragma unroll
    for (int j = 0; j < FN; j++) bfr[j] = *(const bf16x8*)&Bs[(wn + j * 16 + r16) * 32 + q8];
#pragma unroll
    for (int i = 0; i < FM; i++)
#pragma unroll
      for (int j = 0; j < FN; j++)
        acc[i][j] = __builtin_amdgcn_mfma_f32_16x16x32_bf16(afr[i], bfr[j], acc[i][j], 0, 0, 0);
    __syncthreads();
  }

  const int er = (lane >> 4) << 2;
#pragma unroll
  for (int i = 0; i < FM; ++i)
#pragma unroll
    for (int j = 0; j < FN; ++j)
#pragma unroll
      for (int r = 0; r < 4; ++r) {
        const int gm = m0 + wm + i * 16 + er + r;
        const int gn = n0 + wn + j * 16 + r16;
        float v = acc[i][j][r];
        if (EPI == 0) {
          if (gn < Nvalid) C[(size_t)gm * ldc + gn] = v;
        } else if (EPI == 1) {
          const int mm = gm & 1023;
          v += e0[(size_t)mm * DM + gn];
          const size_t idx = (size_t)mm * DI + ((gm >> 10) << 9) + gn;
          C[idx] = v;
          o2[idx] = (unsigned short)f2bf(v);
        } else if (EPI == 2) {
          const float zg = sigmoidf_(v + e0[gn]);
          const float xn = zg * e1[(size_t)gm * DI + gn] +
                           (1.f - zg) * e1[(size_t)gm * DI + DM + gn];
          const size_t idx = (size_t)gm * DM + gn;
          C[idx] = xn;
          o2[idx] = (unsigned short)f2bf(xn);
        } else {
          C[(size_t)gm * ldc + gn] = v + e0[gn];
        }
      }
}

// ---------------------------------------------------------------------------
// One grid-stride conversion for wo + aw + lmw (fp32 -> bf16).
#define WO4  262144
#define AW4  131072
#define LM4  4194304
__global__ void cvt3_k(const float* __restrict__ wo, const float* __restrict__ aw,
                       const float* __restrict__ lmw,
                       unsigned short* __restrict__ woB, unsigned short* __restrict__ awB,
                       unsigned short* __restrict__ lmwB) {
  const int stride = gridDim.x * blockDim.x;
  for (int i = blockIdx.x * blockDim.x + threadIdx.x; i < WO4 + AW4 + LM4; i += stride) {
    int j = i;
    const float4* s; ushort4* d;
    if (j < WO4)            { s = (const float4*)wo;  d = (ushort4*)woB; }
    else if (j < WO4 + AW4) { j -= WO4; s = (const float4*)aw;  d = (ushort4*)awB; }
    else                    { j -= WO4 + AW4; s = (const float4*)lmw; d = (ushort4*)lmwB; }
    d[j] = cvt4(s[j]);
  }
}

// wi (2192 x 512) -> padded bf16 (2304 x 512), pad rows zeroed every call
__global__ void cvt_wi_k(const float* __restrict__ wi, unsigned short* __restrict__ d) {
  const int row = blockIdx.x, l = blockIdx.y;
  ushort4 o; o.x = o.y = o.z = o.w = 0;
  if (row < DPROJ)
    o = cvt4(((const float4*)(wi + ((size_t)l * DPROJ + row) * DM))[threadIdx.x]);
  ((ushort4*)(d + ((size_t)l * NPADIN + row) * DM))[threadIdx.x] = o;
}

__global__ void embed_k(const int* __restrict__ ids, const float* __restrict__ emb,
                        float* __restrict__ Xf, unsigned short* __restrict__ Xb) {
  const int m = blockIdx.x;
  const int row = ids[m];
  float4 v = ((const float4*)(emb + (size_t)row * DM))[threadIdx.x];
  ((float4*)(Xf + (size_t)m * DM))[threadIdx.x] = v;
  ((ushort4*)(Xb + (size_t)m * DM))[threadIdx.x] = cvt4(v);
}

// ---------------------------------------------------------------------------
// Merged depthwise conv: both directions from ONE read of zx (22-tap register
// window), + fused dt/dA computation (on channel-half-0 blocks).
// grid (64, 2): x = (t-block 32) | (ch-half << 5), y = batch.
__global__ __launch_bounds__(256) void conv_k(const float* __restrict__ zx,
    const float* __restrict__ cw, const float* __restrict__ cb,
    const float* __restrict__ dtb, const float* __restrict__ alog,
    float* __restrict__ xact, float* __restrict__ dtt, float* __restrict__ dAt) {
  const int t0 = (blockIdx.x & 31) << 4;
  const int half = blockIdx.x >> 5;
  const int b = blockIdx.y;
  const float* src = zx + (size_t)b * SEQ * DPROJ + DI;
  float* d0 = xact + (size_t)b * SEQ * CONVD;
  float* d1 = xact + (size_t)(2 + b) * SEQ * CONVD;

  for (int cc = 0; cc < 3; ++cc) {
    const int ci = cc * 256 + threadIdx.x;
    if (ci >= 576) break;
    const int c = half * 576 + ci;
    const float w0 = cw[c*4+0], w1 = cw[c*4+1], w2 = cw[c*4+2], w3 = cw[c*4+3];
    const float bias = cb[c];
    float a_[22];
#pragma unroll
    for (int j = 0; j < 22; ++j) {
      const int t = t0 - 3 + j;
      a_[j] = (t >= 0 && t < SEQ) ? src[(size_t)t * DPROJ + c] : 0.f;
    }
#pragma unroll
    for (int tt = 0; tt < 16; ++tt) {
      const float f = bias + w0*a_[tt]   + w1*a_[tt+1] + w2*a_[tt+2] + w3*a_[tt+3];
      const float g = bias + w3*a_[tt+3] + w2*a_[tt+4] + w1*a_[tt+5] + w0*a_[tt+6];
      d0[(size_t)(t0+tt) * CONVD + c] = siluf_(f);
      d1[(size_t)(t0+tt) * CONVD + c] = siluf_(g);
    }
  }
  if (half == 0) {
    const int hh = threadIdx.x >> 4, tt2 = threadIdx.x & 15;
    const int t = t0 + tt2;
    const float v = zx[(size_t)(b * SEQ + t) * DPROJ + 2176 + hh] + dtb[hh];
    const float dt = (v > 15.f) ? v : log1pf(__expf(v));
    const float A = -__expf(alog[hh]);
    dtt[(b * NH + hh) * SEQ + t] = dt;
    dAt[(b * NH + hh) * SEQ + t] = __expf(dt * A);
  }
}

// ---------------------------------------------------------------------------
// SSD scan v2: B/C/x read straight from global per step (L2-served); LDS only
// for the y partial reduction. Block = (dir,b,h,p-half,n-half): 256 blocks.
__global__ __launch_bounds__(256, 1) void scan_k(const float* __restrict__ xact,
    const float* __restrict__ dtt, const float* __restrict__ dAt,
    float* __restrict__ yn) {
  const int bid = blockIdx.x;
  const int dir = bid >> 7, b = (bid >> 6) & 1, h = (bid >> 2) & 15;
  const int ph = (bid >> 1) & 1, nh = bid & 1;
  const int tid = threadIdx.x, pl = tid & 31, nq = tid >> 5;
  const int p = ph * 32 + pl, nb = nq << 2;
  const float* __restrict__ src = xact + (size_t)(dir * 2 + b) * SEQ * CONVD;
  const float* __restrict__ dtp = dtt + (b * NH + h) * SEQ;
  const float* __restrict__ dap = dAt + (b * NH + h) * SEQ;
  float* __restrict__ yrow = yn + (size_t)nh * (4 * SEQ * DI)
      + (size_t)(dir * 2 + b) * SEQ * DI + h * 64 + ph * 32;
  __shared__ float yp[8][16][33];
  float hs[4] = {0.f, 0.f, 0.f, 0.f};

  for (int c0 = 0; c0 < SEQ; c0 += 16) {
#pragma unroll
    for (int s = 0; s < 16; ++s) {
      const int tn = dir ? (SEQ - 1 - (c0 + s)) : (c0 + s);
      const float* row = src + (size_t)tn * CONVD;
      const float dts = dtp[tn];                 // block-uniform -> s_load
      const float das = dap[tn];
      const float xv = row[h * 64 + p];
      const float4 b4 = *(const float4*)(row + DI + nh * 32 + nb);
      const float4 c4 = *(const float4*)(row + DI + DS + nh * 32 + nb);
      const float dtx = dts * xv;
      float ya;
      hs[0] = hs[0] * das + dtx * b4.x; ya  = hs[0] * c4.x;
      hs[1] = hs[1] * das + dtx * b4.y; ya += hs[1] * c4.y;
      hs[2] = hs[2] * das + dtx * b4.z; ya += hs[2] * c4.z;
      hs[3] = hs[3] * das + dtx * b4.w; ya += hs[3] * c4.w;
      yp[nq][s][pl] = ya;
    }
    __syncthreads();
    {
      const int rt = tid >> 4, rp = (tid & 15) << 1;
      const int tn = dir ? (SEQ - 1 - (c0 + rt)) : (c0 + rt);
      float s0 = 0.f, s1 = 0.f;
#pragma unroll
      for (int j = 0; j < 8; ++j) { s0 += yp[j][rt][rp]; s1 += yp[j][rt][rp + 1]; }
      float2 o; o.x = s0; o.y = s1;
      *(float2*)&yrow[(size_t)tn * DI + rp] = o;
    }
    __syncthreads();
  }
}

// gated = (y0+y1 + xs*D[h]) * silu(z); A2b = bf16(rmsnorm(gated) * norm_w)
__global__ __launch_bounds__(256) void p2_k(const float* __restrict__ yn,
    const float* __restrict__ xact, const float* __restrict__ zx,
    const float* __restrict__ dss, const float* __restrict__ nw,
    unsigned short* __restrict__ A2b) {
  const int m2 = blockIdx.x;
  const int e4 = threadIdx.x << 2;
  const float4 ya = *(const float4*)(yn + (size_t)m2 * DI + e4);
  const float4 yb = *(const float4*)(yn + (size_t)4 * SEQ * DI + (size_t)m2 * DI + e4);
  const float4 x4 = *(const float4*)(xact + (size_t)m2 * CONVD + e4);
  const float4 z4 = *(const float4*)(zx + (size_t)(m2 & 1023) * DPROJ + e4);
  const float d = dss[e4 >> 6];
  float4 g;
  g.x = (ya.x + yb.x + x4.x * d) * siluf_(z4.x);
  g.y = (ya.y + yb.y + x4.y * d) * siluf_(z4.y);
  g.z = (ya.z + yb.z + x4.z * d) * siluf_(z4.z);
  g.w = (ya.w + yb.w + x4.w * d) * siluf_(z4.w);
  float ss = g.x*g.x + g.y*g.y + g.z*g.z + g.w*g.w;
#pragma unroll
  for (int m = 32; m >= 1; m >>= 1) ss += __shfl_xor(ss, m);
  __shared__ float red[4];
  if ((threadIdx.x & 63) == 0) red[threadIdx.x >> 6] = ss;
  __syncthreads();
  const float tot = red[0] + red[1] + red[2] + red[3];
  const float sc = rsqrtf(tot * (1.f / 1024.f) + 1e-5f);
  const float4 w4 = *(const float4*)(nw + e4);
  float4 o;
  o.x = g.x * sc * w4.x; o.y = g.y * sc * w4.y;
  o.z = g.z * sc * w4.z; o.w = g.w * sc * w4.w;
  ((ushort4*)(A2b + (size_t)m2 * DI))[threadIdx.x] = cvt4(o);
}

__global__ __launch_bounds__(128) void fnorm_k(const float* __restrict__ X,
    const float* __restrict__ w, unsigned short* __restrict__ outb) {
  const int m = blockIdx.x;
  const int e4 = threadIdx.x << 2;
  const float4 x4 = *(const float4*)(X + (size_t)m * DM + e4);
  float ss = x4.x*x4.x + x4.y*x4.y + x4.z*x4.z + x4.w*x4.w;
#pragma unroll
  for (int mm = 32; mm >= 1; mm >>= 1) ss += __shfl_xor(ss, mm);
  __shared__ float red[2];
  if ((threadIdx.x & 63) == 0) red[threadIdx.x >> 6] = ss;
  __syncthreads();
  const float tot = red[0] + red[1];
  const float sc = rsqrtf(tot * (1.f / 512.f) + 1e-5f);
  const float4 w4 = *(const float4*)(w + e4);
  float4 o;
  o.x = x4.x * sc * w4.x; o.y = x4.y * sc * w4.y;
  o.z = x4.z * sc * w4.z; o.w = x4.w * sc * w4.w;
  ((ushort4*)(outb + (size_t)m * DM))[threadIdx.x] = cvt4(o);
}

// ---------------------------------------------------------------------------
extern "C" void kernel_launch(void* const* d_in, const int* in_sizes, int n_in,
                              void* d_out, int out_size, void* d_ws, size_t ws_size,
                              hipStream_t stream) {
  (void)in_sizes; (void)n_in; (void)out_size; (void)ws_size;
  const int*   ids  = (const int*)d_in[0];
  const float* emb  = (const float*)d_in[2];
  const float* wi   = (const float*)d_in[3];
  const float* cw   = (const float*)d_in[4];
  const float* cb   = (const float*)d_in[5];
  const float* dtb  = (const float*)d_in[6];
  const float* alog = (const float*)d_in[7];
  const float* dss  = (const float*)d_in[8];
  const float* nw   = (const float*)d_in[9];
  const float* wo   = (const float*)d_in[10];
  const float* aw   = (const float*)d_in[11];
  const float* ab   = (const float*)d_in[12];
  const float* nfw  = (const float*)d_in[13];
  const float* lmw  = (const float*)d_in[14];
  const float* lmb  = (const float*)d_in[15];
  float* out = (float*)d_out;

  float* ws    = (float*)d_ws;
  float* Xf    = ws;                                 //  524288
  float* zx    = Xf    + (size_t)524288;             // 2244608
  float* xact  = zx    + (size_t)2244608;            // 2359296
  float* dtt   = xact  + (size_t)2359296;            //   16384
  float* dAt   = dtt   + (size_t)16384;              //   16384
  float* yn    = dAt   + (size_t)16384;              // 4194304 (2 halves)
  float* Xcatf = yn    + (size_t)4194304;            // 1048576
  unsigned short* Xb    = (unsigned short*)(Xcatf + (size_t)1048576);
  unsigned short* A2b   = Xb    + (size_t)524288;
  unsigned short* Xcatb = A2b   + (size_t)2097152;
  unsigned short* hnb   = Xcatb + (size_t)1048576;
  unsigned short* wiB   = hnb   + (size_t)524288;
  unsigned short* woB   = wiB   + (size_t)2359296;
  unsigned short* awB   = woB   + (size_t)1048576;
  unsigned short* lmwB  = awB   + (size_t)524288;

  cvt_wi_k<<<dim3(NPADIN, 2), dim3(128), 0, stream>>>(wi, wiB);
  cvt3_k<<<dim3(4480), dim3(256), 0, stream>>>(wo, aw, lmw, woB, awB, lmwB);
  embed_k<<<dim3(1024), dim3(128), 0, stream>>>(ids, emb, Xf, Xb);

  for (int layer = 0; layer < 2; ++layer) {
    gemm_bf<128, 128, 0><<<dim3(18, 8), dim3(256), 0, stream>>>(
        (const short*)Xb, (const short*)(wiB + (size_t)layer * NPADIN * DM),
        zx, 512, 2192, 2192, nullptr, nullptr, nullptr);
    conv_k<<<dim3(64, 2), dim3(256), 0, stream>>>(
        zx, cw + (size_t)layer * 4608, cb + (size_t)layer * 1152,
        dtb + 16 * layer, alog + 16 * layer, xact, dtt, dAt);
    scan_k<<<dim3(256), dim3(256), 0, stream>>>(xact, dtt, dAt, yn);
    p2_k<<<dim3(2048), dim3(256), 0, stream>>>(yn, xact, zx, dss + 16 * layer,
                                               nw + (size_t)layer * 1024, A2b);
    gemm_bf<64, 128, 1><<<dim3(4, 32), dim3(256), 0, stream>>>(
        (const short*)A2b, (const short*)(woB + (size_t)layer * DM * DI),
        Xcatf, 1024, 512, 512, Xf, nullptr, Xcatb);
    gemm_bf<64, 64, 2><<<dim3(8, 16), dim3(256), 0, stream>>>(
        (const short*)Xcatb, (const short*)awB,
        Xf, 1024, 512, 512, ab, Xcatf, Xb);
  }
  fnorm_k<<<dim3(1024), dim3(128), 0, stream>>>(Xf, nfw, hnb);
  gemm_bf<128, 128, 3><<<dim3(256, 8), dim3(256), 0, stream>>>(
      (const short*)hnb, (const short*)lmwB, out, 512, 32768, 32768, lmb, nullptr, nullptr);
}

// Round 4
// 514.215 us; speedup vs baseline: 1.5325x; 1.0787x over previous
//
#include <hip/hip_runtime.h>

#define SEQ    512
#define DM     512
#define DI     1024
#define NH     16
#define DS     64
#define CONVD  1152
#define DPROJ  2192
#define NPADIN 2304

typedef __attribute__((ext_vector_type(8))) short bf16x8;
typedef __attribute__((ext_vector_type(4))) float floatx4;

__device__ __forceinline__ unsigned int f2bf(float f) {
  unsigned int u = __float_as_uint(f);
  u += 0x7FFFu + ((u >> 16) & 1u);   // RNE
  return u >> 16;
}
__device__ __forceinline__ ushort4 cvt4(float4 v) {
  ushort4 o;
  o.x = (unsigned short)f2bf(v.x); o.y = (unsigned short)f2bf(v.y);
  o.z = (unsigned short)f2bf(v.z); o.w = (unsigned short)f2bf(v.w);
  return o;
}
__device__ __forceinline__ float sigmoidf_(float x) { return 1.f / (1.f + __expf(-x)); }
__device__ __forceinline__ float siluf_(float x) { return x * sigmoidf_(x); }

__device__ __forceinline__ void gl16(const void* g, void* l) {
  __builtin_amdgcn_global_load_lds(
      (const __attribute__((address_space(1))) unsigned int*)g,
      (__attribute__((address_space(3))) unsigned int*)l, 16, 0, 0);
}

// ---------------------------------------------------------------------------
// bf16 C = A * B^T GEMM. BK=64 (half the barrier-iters of BK=32), 128B LDS
// rows with XOR chunk swizzle applied on the per-lane GLOBAL source address
// (gl16's LDS side is forced lane-contiguous), so frag ds_read_b128 sits at
// the LDS BW floor.
// EPI 0: fp32 store, guard gn < Nvalid (in_proj -> zx)
// EPI 1: v += Xf[mm][gn]; Xcat[f+b16][mm][(gm>>10)*512+gn] (out_proj)
// EPI 2: zg=sigmoid(v+bias); xn = zg*Xcatf[..gn]+(1-zg)*Xcatf[..512+gn];
//        store Xf fp32 + Xb bf16 (aggr)
// EPI 3: fp32 store v + bias (lm_head)
// ---------------------------------------------------------------------------
template<int BM, int BN, int EPI>
__global__ __launch_bounds__(256) void gemm_bf(
    const short* __restrict__ A, const short* __restrict__ B,
    float* __restrict__ C, const int K, const int Nvalid, const int ldc,
    const float* __restrict__ e0, const float* __restrict__ e1,
    unsigned short* __restrict__ o2)
{
  constexpr int FM = BM / 32, FN = BN / 32;
  constexpr int PA = BM / 32, PB = BN / 32;   // staging passes (32 rows each)
  __shared__ short As[BM * 64];
  __shared__ short Bs[BN * 64];
  const int tid = threadIdx.x, lane = tid & 63, wave = tid >> 6;
  const int m0 = blockIdx.y * BM, n0 = blockIdx.x * BN;
  const int wm = (wave >> 1) * (BM / 2), wn = (wave & 1) * (BN / 2);
  const int prow = wave * 8 + (lane >> 3);            // row within 32-row pass
  const int schk = ((lane & 7) ^ (prow & 7)) << 3;    // swizzled source chunk
  const short* agp = A + (size_t)(m0 + prow) * K + schk;
  const short* bgp = B + (size_t)(n0 + prow) * K + schk;
  short* albase = &As[wave * 8 * 64];                 // wave-uniform
  short* blbase = &Bs[wave * 8 * 64];
  const int r16 = lane & 15, quad = lane >> 4;

  floatx4 acc[FM][FN];
#pragma unroll
  for (int i = 0; i < FM; i++)
#pragma unroll
    for (int j = 0; j < FN; j++) acc[i][j] = (floatx4)0.f;

  for (int k0 = 0; k0 < K; k0 += 64) {
#pragma unroll
    for (int p = 0; p < PA; ++p)
      gl16(agp + (size_t)p * 32 * K + k0, albase + p * 32 * 64);
#pragma unroll
    for (int p = 0; p < PB; ++p)
      gl16(bgp + (size_t)p * 32 * K + k0, blbase + p * 32 * 64);
    __syncthreads();
#pragma unroll
    for (int kk = 0; kk < 2; ++kk) {
      bf16x8 afr[FM], bfr[FN];
#pragma unroll
      for (int i = 0; i < FM; i++) {
        const int row = wm + i * 16 + r16;
        afr[i] = *(const bf16x8*)&As[row * 64 + (((kk * 4 + quad) ^ (row & 7)) << 3)];
      }
#pragma unroll
      for (int j = 0; j < FN; j++) {
        const int row = wn + j * 16 + r16;
        bfr[j] = *(const bf16x8*)&Bs[row * 64 + (((kk * 4 + quad) ^ (row & 7)) << 3)];
      }
#pragma unroll
      for (int i = 0; i < FM; i++)
#pragma unroll
        for (int j = 0; j < FN; j++)
          acc[i][j] = __builtin_amdgcn_mfma_f32_16x16x32_bf16(afr[i], bfr[j], acc[i][j], 0, 0, 0);
    }
    __syncthreads();
  }

  const int er = quad << 2;
#pragma unroll
  for (int i = 0; i < FM; ++i)
#pragma unroll
    for (int j = 0; j < FN; ++j)
#pragma unroll
      for (int r = 0; r < 4; ++r) {
        const int gm = m0 + wm + i * 16 + er + r;
        const int gn = n0 + wn + j * 16 + r16;
        float v = acc[i][j][r];
        if (EPI == 0) {
          if (gn < Nvalid) C[(size_t)gm * ldc + gn] = v;
        } else if (EPI == 1) {
          const int mm = gm & 1023;
          v += e0[(size_t)mm * DM + gn];
          const size_t idx = (size_t)mm * DI + ((gm >> 10) << 9) + gn;
          C[idx] = v;
          o2[idx] = (unsigned short)f2bf(v);
        } else if (EPI == 2) {
          const float zg = sigmoidf_(v + e0[gn]);
          const float xn = zg * e1[(size_t)gm * DI + gn] +
                           (1.f - zg) * e1[(size_t)gm * DI + DM + gn];
          const size_t idx = (size_t)gm * DM + gn;
          C[idx] = xn;
          o2[idx] = (unsigned short)f2bf(xn);
        } else {
          C[(size_t)gm * ldc + gn] = v + e0[gn];
        }
      }
}

// ---------------------------------------------------------------------------
// One prep launch: embed (512 blocks) + wi convert/pad (2304) + wo/aw/lmw
// convert (4480, grid-stride).
#define WO4  262144
#define AW4  131072
#define LM4  4194304
__global__ __launch_bounds__(256) void prep_k(
    const int* __restrict__ ids, const float* __restrict__ emb,
    const float* __restrict__ wi, const float* __restrict__ wo,
    const float* __restrict__ aw, const float* __restrict__ lmw,
    float* __restrict__ Xf, unsigned short* __restrict__ Xb,
    unsigned short* __restrict__ wiB, unsigned short* __restrict__ woB,
    unsigned short* __restrict__ awB, unsigned short* __restrict__ lmwB) {
  const int blk = blockIdx.x, tid = threadIdx.x;
  if (blk < 512) {
    const int m = blk * 2 + (tid >> 7), col = tid & 127;
    const int row = ids[m];
    float4 v = ((const float4*)(emb + (size_t)row * DM))[col];
    ((float4*)(Xf + (size_t)m * DM))[col] = v;
    ((ushort4*)(Xb + (size_t)m * DM))[col] = cvt4(v);
  } else if (blk < 512 + 2304) {
    const int slot = (blk - 512) * 2 + (tid >> 7), col = tid & 127;
    const int l = slot >= 2304 ? 1 : 0;
    const int row = slot - l * 2304;
    ushort4 o; o.x = o.y = o.z = o.w = 0;
    if (row < DPROJ)
      o = cvt4(((const float4*)(wi + ((size_t)l * DPROJ + row) * DM))[col]);
    ((ushort4*)(wiB + ((size_t)l * NPADIN + row) * DM))[col] = o;
  } else {
    for (int i = (blk - 2816) * 256 + tid; i < WO4 + AW4 + LM4; i += 4480 * 256) {
      int j = i;
      const float4* s; ushort4* d;
      if (j < WO4)            { s = (const float4*)wo;  d = (ushort4*)woB; }
      else if (j < WO4 + AW4) { j -= WO4; s = (const float4*)aw;  d = (ushort4*)awB; }
      else                    { j -= WO4 + AW4; s = (const float4*)lmw; d = (ushort4*)lmwB; }
      d[j] = cvt4(s[j]);
    }
  }
}

// ---------------------------------------------------------------------------
// Merged depthwise conv (both directions, one read of zx) + fused dt/dA.
__global__ __launch_bounds__(256) void conv_k(const float* __restrict__ zx,
    const float* __restrict__ cw, const float* __restrict__ cb,
    const float* __restrict__ dtb, const float* __restrict__ alog,
    float* __restrict__ xact, float* __restrict__ dtt, float* __restrict__ dAt) {
  const int t0 = (blockIdx.x & 31) << 4;
  const int half = blockIdx.x >> 5;
  const int b = blockIdx.y;
  const float* src = zx + (size_t)b * SEQ * DPROJ + DI;
  float* d0 = xact + (size_t)b * SEQ * CONVD;
  float* d1 = xact + (size_t)(2 + b) * SEQ * CONVD;

  for (int cc = 0; cc < 3; ++cc) {
    const int ci = cc * 256 + threadIdx.x;
    if (ci >= 576) break;
    const int c = half * 576 + ci;
    const float w0 = cw[c*4+0], w1 = cw[c*4+1], w2 = cw[c*4+2], w3 = cw[c*4+3];
    const float bias = cb[c];
    float a_[22];
#pragma unroll
    for (int j = 0; j < 22; ++j) {
      const int t = t0 - 3 + j;
      a_[j] = (t >= 0 && t < SEQ) ? src[(size_t)t * DPROJ + c] : 0.f;
    }
#pragma unroll
    for (int tt = 0; tt < 16; ++tt) {
      const float f = bias + w0*a_[tt]   + w1*a_[tt+1] + w2*a_[tt+2] + w3*a_[tt+3];
      const float g = bias + w3*a_[tt+3] + w2*a_[tt+4] + w1*a_[tt+5] + w0*a_[tt+6];
      d0[(size_t)(t0+tt) * CONVD + c] = siluf_(f);
      d1[(size_t)(t0+tt) * CONVD + c] = siluf_(g);
    }
  }
  if (half == 0) {
    const int hh = threadIdx.x >> 4, tt2 = threadIdx.x & 15;
    const int t = t0 + tt2;
    const float v = zx[(size_t)(b * SEQ + t) * DPROJ + 2176 + hh] + dtb[hh];
    const float dt = (v > 15.f) ? v : log1pf(__expf(v));
    const float A = -__expf(alog[hh]);
    dtt[(b * NH + hh) * SEQ + t] = dt;
    dAt[(b * NH + hh) * SEQ + t] = __expf(dt * A);
  }
}

// ---------------------------------------------------------------------------
// SSD scan: B/C/x straight from global (L2-served); double-buffered LDS
// partials -> ONE barrier per 16-step chunk. 256 blocks.
__global__ __launch_bounds__(256, 1) void scan_k(const float* __restrict__ xact,
    const float* __restrict__ dtt, const float* __restrict__ dAt,
    float* __restrict__ yn) {
  const int bid = blockIdx.x;
  const int dir = bid >> 7, b = (bid >> 6) & 1, h = (bid >> 2) & 15;
  const int ph = (bid >> 1) & 1, nh = bid & 1;
  const int tid = threadIdx.x, pl = tid & 31, nq = tid >> 5;
  const int p = ph * 32 + pl, nb = nq << 2;
  const float* __restrict__ src = xact + (size_t)(dir * 2 + b) * SEQ * CONVD;
  const float* __restrict__ dtp = dtt + (b * NH + h) * SEQ;
  const float* __restrict__ dap = dAt + (b * NH + h) * SEQ;
  float* __restrict__ yrow = yn + (size_t)nh * (4 * SEQ * DI)
      + (size_t)(dir * 2 + b) * SEQ * DI + h * 64 + ph * 32;
  __shared__ float yp[2][8][16][33];
  float hs[4] = {0.f, 0.f, 0.f, 0.f};
  int pb = 0;

  for (int c0 = 0; c0 < SEQ; c0 += 16, pb ^= 1) {
#pragma unroll
    for (int s = 0; s < 16; ++s) {
      const int tn = dir ? (SEQ - 1 - (c0 + s)) : (c0 + s);
      const float* row = src + (size_t)tn * CONVD;
      const float dts = dtp[tn];                 // block-uniform -> s_load
      const float das = dap[tn];
      const float xv = row[h * 64 + p];
      const float4 b4 = *(const float4*)(row + DI + nh * 32 + nb);
      const float4 c4 = *(const float4*)(row + DI + DS + nh * 32 + nb);
      const float dtx = dts * xv;
      float ya;
      hs[0] = hs[0] * das + dtx * b4.x; ya  = hs[0] * c4.x;
      hs[1] = hs[1] * das + dtx * b4.y; ya += hs[1] * c4.y;
      hs[2] = hs[2] * das + dtx * b4.z; ya += hs[2] * c4.z;
      hs[3] = hs[3] * das + dtx * b4.w; ya += hs[3] * c4.w;
      yp[pb][nq][s][pl] = ya;
    }
    __syncthreads();
    {
      const int rt = tid >> 4, rp = (tid & 15) << 1;
      const int tn = dir ? (SEQ - 1 - (c0 + rt)) : (c0 + rt);
      float s0 = 0.f, s1 = 0.f;
#pragma unroll
      for (int j = 0; j < 8; ++j) { s0 += yp[pb][j][rt][rp]; s1 += yp[pb][j][rt][rp + 1]; }
      float2 o; o.x = s0; o.y = s1;
      *(float2*)&yrow[(size_t)tn * DI + rp] = o;
    }
  }
}

// gated = (y0+y1 + xs*D[h]) * silu(z); A2b = bf16(rmsnorm(gated) * norm_w)
__global__ __launch_bounds__(256) void p2_k(const float* __restrict__ yn,
    const float* __restrict__ xact, const float* __restrict__ zx,
    const float* __restrict__ dss, const float* __restrict__ nw,
    unsigned short* __restrict__ A2b) {
  const int m2 = blockIdx.x;
  const int e4 = threadIdx.x << 2;
  const float4 ya = *(const float4*)(yn + (size_t)m2 * DI + e4);
  const float4 yb = *(const float4*)(yn + (size_t)4 * SEQ * DI + (size_t)m2 * DI + e4);
  const float4 x4 = *(const float4*)(xact + (size_t)m2 * CONVD + e4);
  const float4 z4 = *(const float4*)(zx + (size_t)(m2 & 1023) * DPROJ + e4);
  const float d = dss[e4 >> 6];
  float4 g;
  g.x = (ya.x + yb.x + x4.x * d) * siluf_(z4.x);
  g.y = (ya.y + yb.y + x4.y * d) * siluf_(z4.y);
  g.z = (ya.z + yb.z + x4.z * d) * siluf_(z4.z);
  g.w = (ya.w + yb.w + x4.w * d) * siluf_(z4.w);
  float ss = g.x*g.x + g.y*g.y + g.z*g.z + g.w*g.w;
#pragma unroll
  for (int m = 32; m >= 1; m >>= 1) ss += __shfl_xor(ss, m);
  __shared__ float red[4];
  if ((threadIdx.x & 63) == 0) red[threadIdx.x >> 6] = ss;
  __syncthreads();
  const float tot = red[0] + red[1] + red[2] + red[3];
  const float sc = rsqrtf(tot * (1.f / 1024.f) + 1e-5f);
  const float4 w4 = *(const float4*)(nw + e4);
  float4 o;
  o.x = g.x * sc * w4.x; o.y = g.y * sc * w4.y;
  o.z = g.z * sc * w4.z; o.w = g.w * sc * w4.w;
  ((ushort4*)(A2b + (size_t)m2 * DI))[threadIdx.x] = cvt4(o);
}

__global__ __launch_bounds__(128) void fnorm_k(const float* __restrict__ X,
    const float* __restrict__ w, unsigned short* __restrict__ outb) {
  const int m = blockIdx.x;
  const int e4 = threadIdx.x << 2;
  const float4 x4 = *(const float4*)(X + (size_t)m * DM + e4);
  float ss = x4.x*x4.x + x4.y*x4.y + x4.z*x4.z + x4.w*x4.w;
#pragma unroll
  for (int mm = 32; mm >= 1; mm >>= 1) ss += __shfl_xor(ss, mm);
  __shared__ float red[2];
  if ((threadIdx.x & 63) == 0) red[threadIdx.x >> 6] = ss;
  __syncthreads();
  const float tot = red[0] + red[1];
  const float sc = rsqrtf(tot * (1.f / 512.f) + 1e-5f);
  const float4 w4 = *(const float4*)(w + e4);
  float4 o;
  o.x = x4.x * sc * w4.x; o.y = x4.y * sc * w4.y;
  o.z = x4.z * sc * w4.z; o.w = x4.w * sc * w4.w;
  ((ushort4*)(outb + (size_t)m * DM))[threadIdx.x] = cvt4(o);
}

// ---------------------------------------------------------------------------
extern "C" void kernel_launch(void* const* d_in, const int* in_sizes, int n_in,
                              void* d_out, int out_size, void* d_ws, size_t ws_size,
                              hipStream_t stream) {
  (void)in_sizes; (void)n_in; (void)out_size; (void)ws_size;
  const int*   ids  = (const int*)d_in[0];
  const float* emb  = (const float*)d_in[2];
  const float* wi   = (const float*)d_in[3];
  const float* cw   = (const float*)d_in[4];
  const float* cb   = (const float*)d_in[5];
  const float* dtb  = (const float*)d_in[6];
  const float* alog = (const float*)d_in[7];
  const float* dss  = (const float*)d_in[8];
  const float* nw   = (const float*)d_in[9];
  const float* wo   = (const float*)d_in[10];
  const float* aw   = (const float*)d_in[11];
  const float* ab   = (const float*)d_in[12];
  const float* nfw  = (const float*)d_in[13];
  const float* lmw  = (const float*)d_in[14];
  const float* lmb  = (const float*)d_in[15];
  float* out = (float*)d_out;

  float* ws    = (float*)d_ws;
  float* Xf    = ws;                                 //  524288
  float* zx    = Xf    + (size_t)524288;             // 2244608
  float* xact  = zx    + (size_t)2244608;            // 2359296
  float* dtt   = xact  + (size_t)2359296;            //   16384
  float* dAt   = dtt   + (size_t)16384;              //   16384
  float* yn    = dAt   + (size_t)16384;              // 4194304 (2 halves)
  float* Xcatf = yn    + (size_t)4194304;            // 1048576
  unsigned short* Xb    = (unsigned short*)(Xcatf + (size_t)1048576);
  unsigned short* A2b   = Xb    + (size_t)524288;
  unsigned short* Xcatb = A2b   + (size_t)2097152;
  unsigned short* hnb   = Xcatb + (size_t)1048576;
  unsigned short* wiB   = hnb   + (size_t)524288;
  unsigned short* woB   = wiB   + (size_t)2359296;
  unsigned short* awB   = woB   + (size_t)1048576;
  unsigned short* lmwB  = awB   + (size_t)524288;

  prep_k<<<dim3(7296), dim3(256), 0, stream>>>(ids, emb, wi, wo, aw, lmw,
                                               Xf, Xb, wiB, woB, awB, lmwB);

  for (int layer = 0; layer < 2; ++layer) {
    gemm_bf<128, 128, 0><<<dim3(18, 8), dim3(256), 0, stream>>>(
        (const short*)Xb, (const short*)(wiB + (size_t)layer * NPADIN * DM),
        zx, 512, 2192, 2192, nullptr, nullptr, nullptr);
    conv_k<<<dim3(64, 2), dim3(256), 0, stream>>>(
        zx, cw + (size_t)layer * 4608, cb + (size_t)layer * 1152,
        dtb + 16 * layer, alog + 16 * layer, xact, dtt, dAt);
    scan_k<<<dim3(256), dim3(256), 0, stream>>>(xact, dtt, dAt, yn);
    p2_k<<<dim3(2048), dim3(256), 0, stream>>>(yn, xact, zx, dss + 16 * layer,
                                               nw + (size_t)layer * 1024, A2b);
    gemm_bf<64, 128, 1><<<dim3(4, 32), dim3(256), 0, stream>>>(
        (const short*)A2b, (const short*)(woB + (size_t)layer * DM * DI),
        Xcatf, 1024, 512, 512, Xf, nullptr, Xcatb);
    gemm_bf<64, 64, 2><<<dim3(8, 16), dim3(256), 0, stream>>>(
        (const short*)Xcatb, (const short*)awB,
        Xf, 1024, 512, 512, ab, Xcatf, Xb);
  }
  fnorm_k<<<dim3(1024), dim3(128), 0, stream>>>(Xf, nfw, hnb);
  gemm_bf<128, 128, 3><<<dim3(256, 8), dim3(256), 0, stream>>>(
      (const short*)hnb, (const short*)lmwB, out, 512, 32768, 32768, lmb, nullptr, nullptr);
}